// Round 3
// baseline (955.822 us; speedup 1.0000x reference)
//
#include <hip/hip_runtime.h>

typedef __attribute__((ext_vector_type(8))) short short8;    // 8 bf16 = 4 VGPRs
typedef __attribute__((ext_vector_type(4))) float float4v;   // MFMA acc
typedef __attribute__((ext_vector_type(4))) float f32x4;

static __device__ __forceinline__ unsigned short f2bf(float x) {
    unsigned u = __float_as_uint(x);
    return (unsigned short)((u + 0x7fffu + ((u >> 16) & 1u)) >> 16);  // RNE
}
static __device__ __forceinline__ int imin(int a, int b) { return a < b ? a : b; }
static __device__ __forceinline__ int imax(int a, int b) { return a > b ? a : b; }

// async global->LDS, 16B per lane; LDS side is wave-base + lane*16 (contiguous)
static __device__ __forceinline__ void gload_lds16(const void* g, void* l) {
    __builtin_amdgcn_global_load_lds(
        (const __attribute__((address_space(1))) void*)g,
        (__attribute__((address_space(3))) void*)l, 16, 0, 0);
}

// per-image strides (in elements)
#define FB16_IMG 16777216ull   // 8 chunks * 256h * 256w * 32cin shorts (32 MiB)
#define FCL_IMG   8388608ull   // 256h * 256w * 128cout shorts (16 MiB)
#define FEAT_IMG 16777216ull   // 256cin * 256h * 256w floats (64 MiB)
#define CHUNK_STRIDE 2097152   // shorts per chunk (65536 * 32)

// ---------------------------------------------------------------------------
// Kernel 0: repack conv weights fp32 -> bf16, [cin_chunk8][tap9][cout128][cin32]
//           + zero the 64B OOB guard block.  (unchanged, known-good)
// ---------------------------------------------------------------------------
__global__ void wprep_kernel(const float* __restrict__ conv_w,
                             unsigned short* __restrict__ wprep,
                             unsigned short* __restrict__ zguard) {
    if (blockIdx.x == 0 && threadIdx.x < 32) zguard[threadIdx.x] = 0;
    int e = blockIdx.x * 256 + threadIdx.x;           // 294912 total
    if (e >= 294912) return;
    int ci = e & 31;
    int t2 = e >> 5;
    int co = t2 & 127;
    int t3 = t2 >> 7;        // chunk*9 + tap
    int tap = t3 % 9;
    int chunk = t3 / 9;
    int cin = chunk * 32 + ci;
    int ty = tap / 3, tx = tap - ty * 3;
    wprep[e] = f2bf(conv_w[((co * 256 + cin) * 3 + ty) * 3 + tx]);
}

// ---------------------------------------------------------------------------
// Kernel 1: input repack fp32 NCHW -> bf16 [b][chunk8][h][w][cin32]
//           (round-1 layout, reads vectorized to dwordx4).
// Block = (b, chunk, 4-row group). Thread = (row, 4 consecutive pixels).
// Reads: 32x 16B coalesced (1KB/wave/plane). Writes: 16x 16B covering the
// thread's 256B pixel block.
// ---------------------------------------------------------------------------
__global__ __launch_bounds__(256) void prep_kernel(const float* __restrict__ feats,
                                                   unsigned short* __restrict__ fb16) {
    const int bx = blockIdx.x;
    const int b  = bx >> 9;               // image (512 blocks per image)
    const int r  = bx & 511;              // chunk(8) x hgroup(64)
    const int chunk = r >> 6;
    const int hg = r & 63;
    const int t = threadIdx.x;
    const int h  = hg * 4 + (t >> 6);
    const int w4 = (t & 63) * 4;

    const float* src = feats + (size_t)b * FEAT_IMG
                     + (size_t)(chunk * 32) * 65536 + h * 256 + w4;
    unsigned short* dst = fb16 + (size_t)b * FB16_IMG
                        + (size_t)chunk * CHUNK_STRIDE
                        + ((size_t)h * 256 + w4) * 32;
#pragma unroll
    for (int qq = 0; qq < 4; ++qq) {
        f32x4 v[8];
#pragma unroll
        for (int k = 0; k < 8; ++k)
            v[k] = *(const f32x4*)(src + (size_t)(qq * 8 + k) * 65536);
#pragma unroll
        for (int j = 0; j < 4; ++j) {
            short8 o;
#pragma unroll
            for (int k = 0; k < 8; ++k)
                o[k] = (short)f2bf(v[k][j]);
            *(short8*)(dst + j * 32 + qq * 8) = o;   // pixel j, cin qq*8..qq*8+7
        }
    }
}

// ---------------------------------------------------------------------------
// Kernel 2: conv3x3 + bias + BN + ReLU, implicit GEMM.
// Round-1 structure (single LDS buffer, stage -> barrier -> taps -> barrier)
// with an 8-row tile: 128 couts x (8 rows x 32 cols) per block.
// Stage 10x34 pixels (21.8KB). Grid = nb*256 -> 4 blocks/CU co-resident.
// ---------------------------------------------------------------------------
__global__ __launch_bounds__(256, 2) void conv_bn_relu_kernel(
    const unsigned short* __restrict__ fb16_all,  // [b][chunk][h][w][cin32]
    const float* __restrict__ conv_b,
    const float* __restrict__ bn_gamma,
    const float* __restrict__ bn_beta,
    const float* __restrict__ bn_mean,
    const float* __restrict__ bn_var,
    const unsigned short* __restrict__ wprep,
    const unsigned short* __restrict__ zguard,
    unsigned short* __restrict__ feat_cl_all) {   // [b][h][w][128]

    __shared__ __align__(16) unsigned short in_lds[10 * 34 * 32];  // 21760 B
    __shared__ float aL[128], bL[128];

    const int tid = threadIdx.x;
    const int b   = blockIdx.x >> 8;       // image (256 blocks per image)
    const int rem = blockIdx.x & 255;      // ht(32) x wt(8)
    const int h0  = (rem >> 3) * 8;
    const int w0  = (rem & 7) * 32;

    const unsigned short* fb16 = fb16_all + (size_t)b * FB16_IMG;
    unsigned short* feat_cl_b  = feat_cl_all + (size_t)b * FCL_IMG;

    if (tid < 128) {
        float s = bn_gamma[tid] * rsqrtf(bn_var[tid] + 1e-5f);
        aL[tid] = s;
        bL[tid] = (conv_b[tid] - bn_mean[tid]) * s + bn_beta[tid];
    }

    const int wave = tid >> 6;
    const int lane = tid & 63;
    const int q    = lane >> 4;
    const int l15  = lane & 15;

    // ---- staging descriptors: 1360 16B units total, 340 per wave ----------
    // unit u: row=u/136, col=(u%136)>>2, part=(u%136)&3
    int  off_s[6];          // element offset into fb16 chunk slice (shorts)
    int  lds_s[6];          // LDS short offset (= u*8, lane-contiguous)
    bool oob_s[6];
#pragma unroll
    for (int i = 0; i < 6; ++i) {
        int u = wave * 340 + i * 64 + lane;   // i==5: only lane<20 used
        int row = u / 136;
        int r2  = u - row * 136;
        int col = r2 >> 2;
        int part = r2 & 3;
        int gh = h0 - 1 + row;
        int gw = w0 - 1 + col;
        oob_s[i] = ((unsigned)gh > 255u) || ((unsigned)gw > 255u);
        off_s[i] = (gh * 256 + gw) * 32 + part * 8;
        lds_s[i] = u * 8;
    }

    float4v acc[2][16];
#pragma unroll
    for (int a = 0; a < 2; ++a)
#pragma unroll
        for (int p = 0; p < 16; ++p)
            acc[a][p] = (float4v){0.f, 0.f, 0.f, 0.f};

    for (int c = 0; c < 8; ++c) {
        const unsigned short* fb = fb16 + (size_t)c * CHUNK_STRIDE;
#pragma unroll
        for (int i = 0; i < 5; ++i) {
            const unsigned short* gp = oob_s[i] ? zguard : (fb + off_s[i]);
            gload_lds16(gp, &in_lds[lds_s[i]]);
        }
        if (lane < 20) {
            const unsigned short* gp = oob_s[5] ? zguard : (fb + off_s[5]);
            gload_lds16(gp, &in_lds[lds_s[5]]);
        }
        __syncthreads();

#pragma unroll
        for (int tap = 0; tap < 9; ++tap) {
            const int dy = tap / 3, dx = tap - dy * 3;
            const short8* wpt = (const short8*)wprep + (c * 9 + tap) * 512;
            short8 a0 = wpt[(wave * 32 + l15) * 4 + q];          // couts m..m+15
            short8 a1 = wpt[(wave * 32 + 16 + l15) * 4 + q];     // couts m+16..m+31
#pragma unroll
            for (int pt = 0; pt < 16; ++pt) {
                const int r  = pt >> 1;
                const int c0 = (pt & 1) * 16;
                short8 bf = *(const short8*)
                    &in_lds[((r + dy) * 34 + (c0 + l15 + dx)) * 32 + q * 8];
                acc[0][pt] = __builtin_amdgcn_mfma_f32_16x16x32_bf16(a0, bf, acc[0][pt], 0, 0, 0);
                acc[1][pt] = __builtin_amdgcn_mfma_f32_16x16x32_bf16(a1, bf, acc[1][pt], 0, 0, 0);
            }
        }
        __syncthreads();
    }

    // ---- epilogue: bias+BN+ReLU, channels-last bf16 store -----------------
#pragma unroll
    for (int ct = 0; ct < 2; ++ct) {
        const int coutb = wave * 32 + ct * 16 + q * 4;
        const float s0 = aL[coutb + 0], s1 = aL[coutb + 1];
        const float s2 = aL[coutb + 2], s3 = aL[coutb + 3];
        const float o0 = bL[coutb + 0], o1 = bL[coutb + 1];
        const float o2 = bL[coutb + 2], o3 = bL[coutb + 3];
#pragma unroll
        for (int pt = 0; pt < 16; ++pt) {
            const int r  = pt >> 1;
            const int cl = (pt & 1) * 16 + l15;
            float4v v = acc[ct][pt];
            unsigned short p0 = f2bf(fmaxf(v[0] * s0 + o0, 0.f));
            unsigned short p1 = f2bf(fmaxf(v[1] * s1 + o1, 0.f));
            unsigned short p2 = f2bf(fmaxf(v[2] * s2 + o2, 0.f));
            unsigned short p3 = f2bf(fmaxf(v[3] * s3 + o3, 0.f));
            unsigned long long pk = (unsigned long long)p0
                                  | ((unsigned long long)p1 << 16)
                                  | ((unsigned long long)p2 << 32)
                                  | ((unsigned long long)p3 << 48);
            size_t off = ((size_t)((h0 + r) * 256 + (w0 + cl))) * 128 + coutb;
            *(unsigned long long*)(feat_cl_b + off) = pk;
        }
    }
}

// ---------------------------------------------------------------------------
// Kernel 3: masked bilinear RoI gather.  (unchanged)
// ---------------------------------------------------------------------------
__global__ __launch_bounds__(256) void roi_gather_kernel(
    const float* __restrict__ rois,
    const float* __restrict__ masks,
    const unsigned long long* __restrict__ feat_u64,   // feat_cl as 4ch/8B
    float* __restrict__ out) {

    __shared__ int   offs[64][4];
    __shared__ float wts[64][4];

    const int blk = blockIdx.x;            // 512: roi(128) x q0(4)
    const int roi = blk >> 2;
    const int q0  = blk & 3;
    const int tid = threadIdx.x;

    const float* rp = rois + roi * 5;
    const int bi = (int)rp[0];
    int l_ = (int)(rp[1] * 0.25f - 1.0f);
    int t_ = (int)(rp[2] * 0.25f - 1.0f);
    int r_ = (int)(rp[3] * 0.25f + 1.0f);
    int b_ = (int)(rp[4] * 0.25f + 1.0f);
    l_ = imin(imax(l_, 0), 256); t_ = imin(imax(t_, 0), 256);
    r_ = imin(imax(r_, 0), 256); b_ = imin(imax(b_, 0), 256);
    const float ch = (float)(b_ - t_);
    const float cw = (float)(r_ - l_);
    const bool transpose = ch > 1.5f * cw;
    const int chi = imax(b_ - t_, 1);
    const int cwi = imax(r_ - l_, 1);
    const float vscale = ((r_ > l_) && (b_ > t_)) ? 1.f : 0.f;

    {
        const int pos_l  = tid >> 2;
        const int corner = tid & 3;
        const int pos = q0 * 64 + pos_l;
        const int i = pos >> 5, j = pos & 31;
        const float fi = (float)i + 0.5f, fj = (float)j + 0.5f;
        float V = transpose ? (fj * ch * (1.f / 32.f) - 0.5f)
                            : (fi * ch * (1.f / 8.f)  - 0.5f);
        float U = transpose ? (fi * cw * (1.f / 8.f)  - 0.5f)
                            : (fj * cw * (1.f / 32.f) - 0.5f);
        V = fmaxf(V, 0.f); U = fmaxf(U, 0.f);
        float vf = floorf(V), uf = floorf(U);
        int y0 = imin((int)vf, chi - 1); int y1 = imin(y0 + 1, chi - 1);
        int x0 = imin((int)uf, cwi - 1); int x1 = imin(x0 + 1, cwi - 1);
        float wy = V - vf, wx = U - uf;
        int ay = imin(imax(t_ + ((corner & 2) ? y1 : y0), 0), 255);
        int ax = imin(imax(l_ + ((corner & 1) ? x1 : x0), 0), 255);
        float wgt = ((corner & 2) ? wy : (1.f - wy)) * ((corner & 1) ? wx : (1.f - wx));
        wts[pos_l][corner]  = wgt * masks[(size_t)roi * 65536 + ay * 256 + ax] * vscale;
        offs[pos_l][corner] = (ay * 256 + ax) * 32;   // u64 units per pixel row
    }
    __syncthreads();

    const int cq = tid & 31;              // channel quad: ch = 4*cq..4*cq+3
    const int pq = tid >> 5;              // 0..7
    const unsigned long long* fb = feat_u64 + (size_t)bi * (65536ull * 32ull) + cq;
    float* op = out + (size_t)roi * 32768 + (size_t)cq * 4 * 256 + q0 * 64;

#pragma unroll 2
    for (int po = 0; po < 8; ++po) {
        const int pos_l = po * 8 + pq;
        float a0 = 0.f, a1 = 0.f, a2 = 0.f, a3 = 0.f;
#pragma unroll
        for (int k = 0; k < 4; ++k) {
            unsigned long long u = fb[offs[pos_l][k]];
            float w = wts[pos_l][k];
            a0 += w * __uint_as_float((unsigned)(u)       << 16);
            a1 += w * __uint_as_float((unsigned)(u >> 16) << 16);
            a2 += w * __uint_as_float((unsigned)(u >> 32) << 16);
            a3 += w * __uint_as_float((unsigned)(u >> 48) << 16);
        }
        op[pos_l]       = a0;
        op[pos_l + 256] = a1;
        op[pos_l + 512] = a2;
        op[pos_l + 768] = a3;
    }
}

// ---------------------------------------------------------------------------
extern "C" void kernel_launch(void* const* d_in, const int* in_sizes, int n_in,
                              void* d_out, int out_size, void* d_ws, size_t ws_size,
                              hipStream_t stream) {
    const float* feats    = (const float*)d_in[0];
    const float* rois     = (const float*)d_in[1];
    const float* masks    = (const float*)d_in[2];
    const float* conv_w   = (const float*)d_in[3];
    const float* conv_b   = (const float*)d_in[4];
    const float* bn_gamma = (const float*)d_in[5];
    const float* bn_beta  = (const float*)d_in[6];
    const float* bn_mean  = (const float*)d_in[7];
    const float* bn_var   = (const float*)d_in[8];
    float* out = (float*)d_out;

    // ws layout: [wprep 576KB][zguard 64B][... to 1MB][feat_cl 64MB][fb16 4x32MB]
    unsigned short* wprep   = (unsigned short*)d_ws;
    unsigned short* zguard  = (unsigned short*)((char*)d_ws + 0x90000);
    unsigned short* feat_cl = (unsigned short*)((char*)d_ws + (1ull << 20));
    unsigned short* fb16    = (unsigned short*)((char*)d_ws + (1ull << 20) + (64ull << 20));

    const size_t need_merged = (1ull << 20) + (64ull << 20) + (128ull << 20);

    hipLaunchKernelGGL(wprep_kernel, dim3(1152), dim3(256), 0, stream,
                       conv_w, wprep, zguard);

    if (ws_size >= need_merged) {
        // merged path: one prep over all 4 images, one conv over all 4 images
        hipLaunchKernelGGL(prep_kernel, dim3(2048), dim3(256), 0, stream,
                           feats, fb16);
        hipLaunchKernelGGL(conv_bn_relu_kernel, dim3(1024), dim3(256), 0, stream,
                           fb16, conv_b, bn_gamma, bn_beta, bn_mean, bn_var,
                           wprep, zguard, feat_cl);
    } else {
        // fallback: per-batch loop reusing one fb16 image buffer (b folds to 0)
        for (int b = 0; b < 4; ++b) {
            hipLaunchKernelGGL(prep_kernel, dim3(512), dim3(256), 0, stream,
                               feats + (size_t)b * FEAT_IMG, fb16);
            hipLaunchKernelGGL(conv_bn_relu_kernel, dim3(256), dim3(256), 0, stream,
                               fb16, conv_b, bn_gamma, bn_beta, bn_mean, bn_var,
                               wprep, zguard, feat_cl + (size_t)b * FCL_IMG);
        }
    }

    hipLaunchKernelGGL(roi_gather_kernel, dim3(512), dim3(256), 0, stream,
                       rois, masks, (const unsigned long long*)feat_cl, out);
}

// Round 4
// 819.183 us; speedup vs baseline: 1.1668x; 1.1668x over previous
//
#include <hip/hip_runtime.h>

typedef __attribute__((ext_vector_type(8))) short short8;    // 8 bf16 = 4 VGPRs
typedef __attribute__((ext_vector_type(4))) float float4v;   // MFMA acc
typedef __attribute__((ext_vector_type(4))) float f32x4;

static __device__ __forceinline__ unsigned short f2bf(float x) {
    unsigned u = __float_as_uint(x);
    return (unsigned short)((u + 0x7fffu + ((u >> 16) & 1u)) >> 16);  // RNE
}
static __device__ __forceinline__ int imin(int a, int b) { return a < b ? a : b; }
static __device__ __forceinline__ int imax(int a, int b) { return a > b ? a : b; }

// async global->LDS, 16B per lane; LDS side is wave-base + lane*16 (contiguous)
static __device__ __forceinline__ void gload_lds16(const void* g, void* l) {
    __builtin_amdgcn_global_load_lds(
        (const __attribute__((address_space(1))) void*)g,
        (__attribute__((address_space(3))) void*)l, 16, 0, 0);
}

// per-image strides (in elements)
#define FB16_IMG 16777216ull   // 8 chunks * 256h * 256w * 32cin shorts (32 MiB)
#define FCL_IMG   8388608ull   // 256h * 256w * 128cout shorts (16 MiB)
#define FEAT_IMG 16777216ull   // 256cin * 256h * 256w floats (64 MiB)
#define CHUNK_STRIDE 2097152   // shorts per chunk (65536 * 32)

// ---------------------------------------------------------------------------
// Kernel 0: repack conv weights fp32 -> bf16, [cin_chunk8][tap9][cout128][cin32]
//           + zero the 64B OOB guard block.  (unchanged, known-good)
// ---------------------------------------------------------------------------
__global__ void wprep_kernel(const float* __restrict__ conv_w,
                             unsigned short* __restrict__ wprep,
                             unsigned short* __restrict__ zguard) {
    if (blockIdx.x == 0 && threadIdx.x < 32) zguard[threadIdx.x] = 0;
    int e = blockIdx.x * 256 + threadIdx.x;           // 294912 total
    if (e >= 294912) return;
    int ci = e & 31;
    int t2 = e >> 5;
    int co = t2 & 127;
    int t3 = t2 >> 7;        // chunk*9 + tap
    int tap = t3 % 9;
    int chunk = t3 / 9;
    int cin = chunk * 32 + ci;
    int ty = tap / 3, tx = tap - ty * 3;
    wprep[e] = f2bf(conv_w[((co * 256 + cin) * 3 + ty) * 3 + tx]);
}

// ---------------------------------------------------------------------------
// Kernel 1: input repack fp32 NCHW -> bf16 [b][chunk8][h][w][cin32]
//           (dwordx4 reads; unchanged from round 3).
// ---------------------------------------------------------------------------
__global__ __launch_bounds__(256) void prep_kernel(const float* __restrict__ feats,
                                                   unsigned short* __restrict__ fb16) {
    const int bx = blockIdx.x;
    const int b  = bx >> 9;               // image (512 blocks per image)
    const int r  = bx & 511;              // chunk(8) x hgroup(64)
    const int chunk = r >> 6;
    const int hg = r & 63;
    const int t = threadIdx.x;
    const int h  = hg * 4 + (t >> 6);
    const int w4 = (t & 63) * 4;

    const float* src = feats + (size_t)b * FEAT_IMG
                     + (size_t)(chunk * 32) * 65536 + h * 256 + w4;
    unsigned short* dst = fb16 + (size_t)b * FB16_IMG
                        + (size_t)chunk * CHUNK_STRIDE
                        + ((size_t)h * 256 + w4) * 32;
#pragma unroll
    for (int qq = 0; qq < 4; ++qq) {
        f32x4 v[8];
#pragma unroll
        for (int k = 0; k < 8; ++k)
            v[k] = *(const f32x4*)(src + (size_t)(qq * 8 + k) * 65536);
#pragma unroll
        for (int j = 0; j < 4; ++j) {
            short8 o;
#pragma unroll
            for (int k = 0; k < 8; ++k)
                o[k] = (short)f2bf(v[k][j]);
            *(short8*)(dst + j * 32 + qq * 8) = o;   // pixel j, cin qq*8..qq*8+7
        }
    }
}

// ---------------------------------------------------------------------------
// Kernel 2: conv3x3 + bias + BN + ReLU, implicit GEMM.
// Round-1 structure (4-row tile, single LDS buffer, stage->sync->taps->sync)
// with wave remapped: wave = one output ROW x ALL 128 couts.
// Per tap per wave: 8 weight b128 (L2-hot), 2 LDS b128, 16 MFMA
//   -> B-reuse 8x, LDS wall 1728 cyc/CU-chunk < MFMA wall.
// acc[8][2] = 64 regs; launch_bounds(256,2) -> 256-reg budget, no spill.
// ---------------------------------------------------------------------------
__global__ __launch_bounds__(256, 2) void conv_bn_relu_kernel(
    const unsigned short* __restrict__ fb16_all,  // [b][chunk][h][w][cin32]
    const float* __restrict__ conv_b,
    const float* __restrict__ bn_gamma,
    const float* __restrict__ bn_beta,
    const float* __restrict__ bn_mean,
    const float* __restrict__ bn_var,
    const unsigned short* __restrict__ wprep,
    const unsigned short* __restrict__ zguard,
    unsigned short* __restrict__ feat_cl_all) {   // [b][h][w][128]

    __shared__ __align__(16) unsigned short in_lds[6 * 34 * 32];  // 26112 B
    __shared__ float aL[128], bL[128];

    const int tid = threadIdx.x;
    const int b   = blockIdx.x >> 9;       // image (512 blocks per image)
    const int rem = blockIdx.x & 511;      // ht(64) x wt(8)
    const int h0  = (rem >> 3) * 4;
    const int w0  = (rem & 7) * 32;

    const unsigned short* fb16 = fb16_all + (size_t)b * FB16_IMG;
    unsigned short* feat_cl_b  = feat_cl_all + (size_t)b * FCL_IMG;

    if (tid < 128) {
        float s = bn_gamma[tid] * rsqrtf(bn_var[tid] + 1e-5f);
        aL[tid] = s;
        bL[tid] = (conv_b[tid] - bn_mean[tid]) * s + bn_beta[tid];
    }

    const int wave = tid >> 6;
    const int lane = tid & 63;
    const int q    = lane >> 4;
    const int l15  = lane & 15;

    // ---- staging descriptors (round-1 exact): 816 units, wave*204 ---------
    // unit u: row=u/136, col=(u%136)>>2, part=(u%136)&3
    int  off_s[4];          // element offset into fb16 chunk slice (shorts)
    int  lds_s[4];          // LDS short offset (= u*8, lane-contiguous)
    bool oob_s[4];
#pragma unroll
    for (int i = 0; i < 4; ++i) {
        int u = wave * 204 + i * 64 + lane;   // i==3: only lane<12 used
        int row = u / 136;
        int r2  = u - row * 136;
        int col = r2 >> 2;
        int part = r2 & 3;
        int gh = h0 - 1 + row;
        int gw = w0 - 1 + col;
        oob_s[i] = ((unsigned)gh > 255u) || ((unsigned)gw > 255u);
        off_s[i] = (gh * 256 + gw) * 32 + part * 8;
        lds_s[i] = u * 8;
    }

    float4v acc[8][2];
#pragma unroll
    for (int i = 0; i < 8; ++i)
#pragma unroll
        for (int pt = 0; pt < 2; ++pt)
            acc[i][pt] = (float4v){0.f, 0.f, 0.f, 0.f};

    for (int c = 0; c < 8; ++c) {
        const unsigned short* fb = fb16 + (size_t)c * CHUNK_STRIDE;
#pragma unroll
        for (int i = 0; i < 3; ++i) {
            const unsigned short* gp = oob_s[i] ? zguard : (fb + off_s[i]);
            gload_lds16(gp, &in_lds[lds_s[i]]);
        }
        if (lane < 12) {
            const unsigned short* gp = oob_s[3] ? zguard : (fb + off_s[3]);
            gload_lds16(gp, &in_lds[lds_s[3]]);
        }
        __syncthreads();

#pragma unroll
        for (int tap = 0; tap < 9; ++tap) {
            const int dy = tap / 3, dx = tap - dy * 3;
            const short8* wpt = (const short8*)wprep + (c * 9 + tap) * 512;
            // 8 weight fragments cover all 128 couts (L2-hot, shared by all blocks)
            short8 a[8];
#pragma unroll
            for (int i = 0; i < 8; ++i)
                a[i] = wpt[(i * 16 + l15) * 4 + q];
#pragma unroll
            for (int pt = 0; pt < 2; ++pt) {
                // one B-read feeds 8 MFMAs
                short8 bf = *(const short8*)
                    &in_lds[((wave + dy) * 34 + (pt * 16 + l15 + dx)) * 32 + q * 8];
#pragma unroll
                for (int i = 0; i < 8; ++i)
                    acc[i][pt] = __builtin_amdgcn_mfma_f32_16x16x32_bf16(a[i], bf, acc[i][pt], 0, 0, 0);
            }
        }
        __syncthreads();
    }

    // ---- epilogue: bias+BN+ReLU, channels-last bf16 store -----------------
    // C/D layout: col(pixel)=lane&15, row(cout-within-tile)=q*4+reg
#pragma unroll
    for (int i = 0; i < 8; ++i) {
        const int coutb = i * 16 + q * 4;
        const float s0 = aL[coutb + 0], s1 = aL[coutb + 1];
        const float s2 = aL[coutb + 2], s3 = aL[coutb + 3];
        const float o0 = bL[coutb + 0], o1 = bL[coutb + 1];
        const float o2 = bL[coutb + 2], o3 = bL[coutb + 3];
#pragma unroll
        for (int pt = 0; pt < 2; ++pt) {
            float4v v = acc[i][pt];
            unsigned short p0 = f2bf(fmaxf(v[0] * s0 + o0, 0.f));
            unsigned short p1 = f2bf(fmaxf(v[1] * s1 + o1, 0.f));
            unsigned short p2 = f2bf(fmaxf(v[2] * s2 + o2, 0.f));
            unsigned short p3 = f2bf(fmaxf(v[3] * s3 + o3, 0.f));
            unsigned long long pk = (unsigned long long)p0
                                  | ((unsigned long long)p1 << 16)
                                  | ((unsigned long long)p2 << 32)
                                  | ((unsigned long long)p3 << 48);
            size_t off = ((size_t)((h0 + wave) * 256 + (w0 + pt * 16 + l15))) * 128 + coutb;
            *(unsigned long long*)(feat_cl_b + off) = pk;
        }
    }
}

// ---------------------------------------------------------------------------
// Kernel 3: masked bilinear RoI gather.  (unchanged)
// ---------------------------------------------------------------------------
__global__ __launch_bounds__(256) void roi_gather_kernel(
    const float* __restrict__ rois,
    const float* __restrict__ masks,
    const unsigned long long* __restrict__ feat_u64,   // feat_cl as 4ch/8B
    float* __restrict__ out) {

    __shared__ int   offs[64][4];
    __shared__ float wts[64][4];

    const int blk = blockIdx.x;            // 512: roi(128) x q0(4)
    const int roi = blk >> 2;
    const int q0  = blk & 3;
    const int tid = threadIdx.x;

    const float* rp = rois + roi * 5;
    const int bi = (int)rp[0];
    int l_ = (int)(rp[1] * 0.25f - 1.0f);
    int t_ = (int)(rp[2] * 0.25f - 1.0f);
    int r_ = (int)(rp[3] * 0.25f + 1.0f);
    int b_ = (int)(rp[4] * 0.25f + 1.0f);
    l_ = imin(imax(l_, 0), 256); t_ = imin(imax(t_, 0), 256);
    r_ = imin(imax(r_, 0), 256); b_ = imin(imax(b_, 0), 256);
    const float ch = (float)(b_ - t_);
    const float cw = (float)(r_ - l_);
    const bool transpose = ch > 1.5f * cw;
    const int chi = imax(b_ - t_, 1);
    const int cwi = imax(r_ - l_, 1);
    const float vscale = ((r_ > l_) && (b_ > t_)) ? 1.f : 0.f;

    {
        const int pos_l  = tid >> 2;
        const int corner = tid & 3;
        const int pos = q0 * 64 + pos_l;
        const int i = pos >> 5, j = pos & 31;
        const float fi = (float)i + 0.5f, fj = (float)j + 0.5f;
        float V = transpose ? (fj * ch * (1.f / 32.f) - 0.5f)
                            : (fi * ch * (1.f / 8.f)  - 0.5f);
        float U = transpose ? (fi * cw * (1.f / 8.f)  - 0.5f)
                            : (fj * cw * (1.f / 32.f) - 0.5f);
        V = fmaxf(V, 0.f); U = fmaxf(U, 0.f);
        float vf = floorf(V), uf = floorf(U);
        int y0 = imin((int)vf, chi - 1); int y1 = imin(y0 + 1, chi - 1);
        int x0 = imin((int)uf, cwi - 1); int x1 = imin(x0 + 1, cwi - 1);
        float wy = V - vf, wx = U - uf;
        int ay = imin(imax(t_ + ((corner & 2) ? y1 : y0), 0), 255);
        int ax = imin(imax(l_ + ((corner & 1) ? x1 : x0), 0), 255);
        float wgt = ((corner & 2) ? wy : (1.f - wy)) * ((corner & 1) ? wx : (1.f - wx));
        wts[pos_l][corner]  = wgt * masks[(size_t)roi * 65536 + ay * 256 + ax] * vscale;
        offs[pos_l][corner] = (ay * 256 + ax) * 32;   // u64 units per pixel row
    }
    __syncthreads();

    const int cq = tid & 31;              // channel quad: ch = 4*cq..4*cq+3
    const int pq = tid >> 5;              // 0..7
    const unsigned long long* fb = feat_u64 + (size_t)bi * (65536ull * 32ull) + cq;
    float* op = out + (size_t)roi * 32768 + (size_t)cq * 4 * 256 + q0 * 64;

#pragma unroll 2
    for (int po = 0; po < 8; ++po) {
        const int pos_l = po * 8 + pq;
        float a0 = 0.f, a1 = 0.f, a2 = 0.f, a3 = 0.f;
#pragma unroll
        for (int k = 0; k < 4; ++k) {
            unsigned long long u = fb[offs[pos_l][k]];
            float w = wts[pos_l][k];
            a0 += w * __uint_as_float((unsigned)(u)       << 16);
            a1 += w * __uint_as_float((unsigned)(u >> 16) << 16);
            a2 += w * __uint_as_float((unsigned)(u >> 32) << 16);
            a3 += w * __uint_as_float((unsigned)(u >> 48) << 16);
        }
        op[pos_l]       = a0;
        op[pos_l + 256] = a1;
        op[pos_l + 512] = a2;
        op[pos_l + 768] = a3;
    }
}

// ---------------------------------------------------------------------------
extern "C" void kernel_launch(void* const* d_in, const int* in_sizes, int n_in,
                              void* d_out, int out_size, void* d_ws, size_t ws_size,
                              hipStream_t stream) {
    const float* feats    = (const float*)d_in[0];
    const float* rois     = (const float*)d_in[1];
    const float* masks    = (const float*)d_in[2];
    const float* conv_w   = (const float*)d_in[3];
    const float* conv_b   = (const float*)d_in[4];
    const float* bn_gamma = (const float*)d_in[5];
    const float* bn_beta  = (const float*)d_in[6];
    const float* bn_mean  = (const float*)d_in[7];
    const float* bn_var   = (const float*)d_in[8];
    float* out = (float*)d_out;

    // ws layout: [wprep 576KB][zguard 64B][... to 1MB][feat_cl 64MB][fb16 4x32MB]
    unsigned short* wprep   = (unsigned short*)d_ws;
    unsigned short* zguard  = (unsigned short*)((char*)d_ws + 0x90000);
    unsigned short* feat_cl = (unsigned short*)((char*)d_ws + (1ull << 20));
    unsigned short* fb16    = (unsigned short*)((char*)d_ws + (1ull << 20) + (64ull << 20));

    const size_t need_merged = (1ull << 20) + (64ull << 20) + (128ull << 20);

    hipLaunchKernelGGL(wprep_kernel, dim3(1152), dim3(256), 0, stream,
                       conv_w, wprep, zguard);

    if (ws_size >= need_merged) {
        // merged path: one prep over all 4 images, one conv over all 4 images
        hipLaunchKernelGGL(prep_kernel, dim3(2048), dim3(256), 0, stream,
                           feats, fb16);
        hipLaunchKernelGGL(conv_bn_relu_kernel, dim3(2048), dim3(256), 0, stream,
                           fb16, conv_b, bn_gamma, bn_beta, bn_mean, bn_var,
                           wprep, zguard, feat_cl);
    } else {
        // fallback: per-batch loop reusing one fb16 image buffer (b folds to 0)
        for (int b = 0; b < 4; ++b) {
            hipLaunchKernelGGL(prep_kernel, dim3(512), dim3(256), 0, stream,
                               feats + (size_t)b * FEAT_IMG, fb16);
            hipLaunchKernelGGL(conv_bn_relu_kernel, dim3(512), dim3(256), 0, stream,
                               fb16, conv_b, bn_gamma, bn_beta, bn_mean, bn_var,
                               wprep, zguard, feat_cl + (size_t)b * FCL_IMG);
        }
    }

    hipLaunchKernelGGL(roi_gather_kernel, dim3(512), dim3(256), 0, stream,
                       rois, masks, (const unsigned long long*)feat_cl, out);
}

// Round 5
// 621.995 us; speedup vs baseline: 1.5367x; 1.3170x over previous
//
#include <hip/hip_runtime.h>

typedef __attribute__((ext_vector_type(8))) short short8;    // 8 bf16 = 4 VGPRs
typedef __attribute__((ext_vector_type(4))) float float4v;   // MFMA acc
typedef __attribute__((ext_vector_type(4))) float f32x4;

static __device__ __forceinline__ unsigned short f2bf(float x) {
    unsigned u = __float_as_uint(x);
    return (unsigned short)((u + 0x7fffu + ((u >> 16) & 1u)) >> 16);  // RNE
}
static __device__ __forceinline__ int imin(int a, int b) { return a < b ? a : b; }
static __device__ __forceinline__ int imax(int a, int b) { return a > b ? a : b; }

// async global->LDS, 16B per lane; LDS side is wave-base + lane*16 (contiguous)
static __device__ __forceinline__ void gload_lds16(const void* g, void* l) {
    __builtin_amdgcn_global_load_lds(
        (const __attribute__((address_space(1))) void*)g,
        (__attribute__((address_space(3))) void*)l, 16, 0, 0);
}

// per-image strides (in elements)
#define FB16_IMG 16777216ull   // 8 chunks * 256h * 256w * 32cin shorts (32 MiB)
#define FCL_IMG   8388608ull   // 256h * 256w * 128cout shorts (16 MiB)
#define FEAT_IMG 16777216ull   // 256cin * 256h * 256w floats (64 MiB)
#define CHUNK_STRIDE 2097152   // shorts per chunk (65536 * 32)

// ---------------------------------------------------------------------------
// Kernel 0: repack conv weights fp32 -> bf16, [cin_chunk8][tap9][cout128][cin32]
//           + zero the 64B OOB guard block.  (unchanged, known-good)
// ---------------------------------------------------------------------------
__global__ void wprep_kernel(const float* __restrict__ conv_w,
                             unsigned short* __restrict__ wprep,
                             unsigned short* __restrict__ zguard) {
    if (blockIdx.x == 0 && threadIdx.x < 32) zguard[threadIdx.x] = 0;
    int e = blockIdx.x * 256 + threadIdx.x;           // 294912 total
    if (e >= 294912) return;
    int ci = e & 31;
    int t2 = e >> 5;
    int co = t2 & 127;
    int t3 = t2 >> 7;        // chunk*9 + tap
    int tap = t3 % 9;
    int chunk = t3 / 9;
    int cin = chunk * 32 + ci;
    int ty = tap / 3, tx = tap - ty * 3;
    wprep[e] = f2bf(conv_w[((co * 256 + cin) * 3 + ty) * 3 + tx]);
}

// ---------------------------------------------------------------------------
// Kernel 1: input repack fp32 NCHW -> bf16 [b][chunk8][h][w][cin32]
//           (dwordx4 reads; unchanged).
// ---------------------------------------------------------------------------
__global__ __launch_bounds__(256) void prep_kernel(const float* __restrict__ feats,
                                                   unsigned short* __restrict__ fb16) {
    const int bx = blockIdx.x;
    const int b  = bx >> 9;               // image (512 blocks per image)
    const int r  = bx & 511;              // chunk(8) x hgroup(64)
    const int chunk = r >> 6;
    const int hg = r & 63;
    const int t = threadIdx.x;
    const int h  = hg * 4 + (t >> 6);
    const int w4 = (t & 63) * 4;

    const float* src = feats + (size_t)b * FEAT_IMG
                     + (size_t)(chunk * 32) * 65536 + h * 256 + w4;
    unsigned short* dst = fb16 + (size_t)b * FB16_IMG
                        + (size_t)chunk * CHUNK_STRIDE
                        + ((size_t)h * 256 + w4) * 32;
#pragma unroll
    for (int qq = 0; qq < 4; ++qq) {
        f32x4 v[8];
#pragma unroll
        for (int k = 0; k < 8; ++k)
            v[k] = *(const f32x4*)(src + (size_t)(qq * 8 + k) * 65536);
#pragma unroll
        for (int j = 0; j < 4; ++j) {
            short8 o;
#pragma unroll
            for (int k = 0; k < 8; ++k)
                o[k] = (short)f2bf(v[k][j]);
            *(short8*)(dst + j * 32 + qq * 8) = o;   // pixel j, cin qq*8..qq*8+7
        }
    }
}

// ---------------------------------------------------------------------------
// Kernel 2: conv3x3 + bias + BN + ReLU, implicit GEMM.
// Round-1 mapping (wave = 32 couts x 128 pixels, acc[2][8]) with:
//  (a) all 18 weight fragments hoisted to registers per chunk (one L2 burst,
//      overlapped with the staging drain; no global loads in the tap loop)
//  (b) dy-reuse loop order (dx, input-row rho, half): one LDS B-read serves
//      up to 3 output rows -> 36 ds_read_b128/wave/chunk instead of 72.
// ---------------------------------------------------------------------------
__global__ __launch_bounds__(256, 2) void conv_bn_relu_kernel(
    const unsigned short* __restrict__ fb16_all,  // [b][chunk][h][w][cin32]
    const float* __restrict__ conv_b,
    const float* __restrict__ bn_gamma,
    const float* __restrict__ bn_beta,
    const float* __restrict__ bn_mean,
    const float* __restrict__ bn_var,
    const unsigned short* __restrict__ wprep,
    const unsigned short* __restrict__ zguard,
    unsigned short* __restrict__ feat_cl_all) {   // [b][h][w][128]

    __shared__ __align__(16) unsigned short in_lds[6 * 34 * 32];  // 13056 B
    __shared__ float aL[128], bL[128];

    const int tid = threadIdx.x;
    const int b   = blockIdx.x >> 9;       // image (512 blocks per image)
    const int rem = blockIdx.x & 511;      // ht(64) x wt(8)
    const int h0  = (rem >> 3) * 4;
    const int w0  = (rem & 7) * 32;

    const unsigned short* fb16 = fb16_all + (size_t)b * FB16_IMG;
    unsigned short* feat_cl_b  = feat_cl_all + (size_t)b * FCL_IMG;

    if (tid < 128) {
        float s = bn_gamma[tid] * rsqrtf(bn_var[tid] + 1e-5f);
        aL[tid] = s;
        bL[tid] = (conv_b[tid] - bn_mean[tid]) * s + bn_beta[tid];
    }

    const int wave = tid >> 6;
    const int lane = tid & 63;
    const int q    = lane >> 4;
    const int l15  = lane & 15;

    // ---- staging descriptors (round-1 exact): 816 units, wave*204 ---------
    // unit u: row=u/136, col=(u%136)>>2, part=(u%136)&3
    int  off_s[4];          // element offset into fb16 chunk slice (shorts)
    int  lds_s[4];          // LDS short offset (= u*8, lane-contiguous)
    bool oob_s[4];
#pragma unroll
    for (int i = 0; i < 4; ++i) {
        int u = wave * 204 + i * 64 + lane;   // i==3: only lane<12 used
        int row = u / 136;
        int r2  = u - row * 136;
        int col = r2 >> 2;
        int part = r2 & 3;
        int gh = h0 - 1 + row;
        int gw = w0 - 1 + col;
        oob_s[i] = ((unsigned)gh > 255u) || ((unsigned)gw > 255u);
        off_s[i] = (gh * 256 + gw) * 32 + part * 8;
        lds_s[i] = u * 8;
    }

    float4v acc[2][8];
#pragma unroll
    for (int a = 0; a < 2; ++a)
#pragma unroll
        for (int p = 0; p < 8; ++p)
            acc[a][p] = (float4v){0.f, 0.f, 0.f, 0.f};

    for (int c = 0; c < 8; ++c) {
        const unsigned short* fb = fb16 + (size_t)c * CHUNK_STRIDE;
        // ---- issue staging DMAs ----
#pragma unroll
        for (int i = 0; i < 3; ++i) {
            const unsigned short* gp = oob_s[i] ? zguard : (fb + off_s[i]);
            gload_lds16(gp, &in_lds[lds_s[i]]);
        }
        if (lane < 12) {
            const unsigned short* gp = oob_s[3] ? zguard : (fb + off_s[3]);
            gload_lds16(gp, &in_lds[lds_s[3]]);
        }

        // ---- hoist all 18 weight fragments for this chunk (independent
        //      L2 loads; overlap the staging drain below) ----
        const short8* wc = (const short8*)wprep + (size_t)c * 9 * 512;
        short8 w0f[9], w1f[9];
#pragma unroll
        for (int tap = 0; tap < 9; ++tap) {
            w0f[tap] = wc[tap * 512 + (wave * 32 + l15) * 4 + q];
            w1f[tap] = wc[tap * 512 + (wave * 32 + 16 + l15) * 4 + q];
        }

        __syncthreads();   // drains DMAs (and the weight burst)

        // ---- dy-reuse tap loop: 36 LDS reads, 144 MFMAs per wave ----
#pragma unroll
        for (int dx = 0; dx < 3; ++dx) {
#pragma unroll
            for (int rho = 0; rho < 6; ++rho) {
#pragma unroll
                for (int half = 0; half < 2; ++half) {
                    short8 bf = *(const short8*)
                        &in_lds[(rho * 34 + (half * 16 + l15 + dx)) * 32 + q * 8];
#pragma unroll
                    for (int dy = 0; dy < 3; ++dy) {
                        const int r = rho - dy;
                        if (r >= 0 && r <= 3) {
                            const int tap = dy * 3 + dx;
                            const int pt  = r * 2 + half;
                            acc[0][pt] = __builtin_amdgcn_mfma_f32_16x16x32_bf16(
                                w0f[tap], bf, acc[0][pt], 0, 0, 0);
                            acc[1][pt] = __builtin_amdgcn_mfma_f32_16x16x32_bf16(
                                w1f[tap], bf, acc[1][pt], 0, 0, 0);
                        }
                    }
                }
            }
        }
        __syncthreads();
    }

    // ---- epilogue: bias+BN+ReLU, channels-last bf16 store (round-1 exact) --
#pragma unroll
    for (int ct = 0; ct < 2; ++ct) {
        const int coutb = wave * 32 + ct * 16 + q * 4;
        const float s0 = aL[coutb + 0], s1 = aL[coutb + 1];
        const float s2 = aL[coutb + 2], s3 = aL[coutb + 3];
        const float o0 = bL[coutb + 0], o1 = bL[coutb + 1];
        const float o2 = bL[coutb + 2], o3 = bL[coutb + 3];
#pragma unroll
        for (int pt = 0; pt < 8; ++pt) {
            const int r  = pt >> 1;
            const int cl = (pt & 1) * 16 + l15;
            float4v v = acc[ct][pt];
            unsigned short p0 = f2bf(fmaxf(v[0] * s0 + o0, 0.f));
            unsigned short p1 = f2bf(fmaxf(v[1] * s1 + o1, 0.f));
            unsigned short p2 = f2bf(fmaxf(v[2] * s2 + o2, 0.f));
            unsigned short p3 = f2bf(fmaxf(v[3] * s3 + o3, 0.f));
            unsigned long long pk = (unsigned long long)p0
                                  | ((unsigned long long)p1 << 16)
                                  | ((unsigned long long)p2 << 32)
                                  | ((unsigned long long)p3 << 48);
            size_t off = ((size_t)((h0 + r) * 256 + (w0 + cl))) * 128 + coutb;
            *(unsigned long long*)(feat_cl_b + off) = pk;
        }
    }
}

// ---------------------------------------------------------------------------
// Kernel 3: masked bilinear RoI gather.  (unchanged)
// ---------------------------------------------------------------------------
__global__ __launch_bounds__(256) void roi_gather_kernel(
    const float* __restrict__ rois,
    const float* __restrict__ masks,
    const unsigned long long* __restrict__ feat_u64,   // feat_cl as 4ch/8B
    float* __restrict__ out) {

    __shared__ int   offs[64][4];
    __shared__ float wts[64][4];

    const int blk = blockIdx.x;            // 512: roi(128) x q0(4)
    const int roi = blk >> 2;
    const int q0  = blk & 3;
    const int tid = threadIdx.x;

    const float* rp = rois + roi * 5;
    const int bi = (int)rp[0];
    int l_ = (int)(rp[1] * 0.25f - 1.0f);
    int t_ = (int)(rp[2] * 0.25f - 1.0f);
    int r_ = (int)(rp[3] * 0.25f + 1.0f);
    int b_ = (int)(rp[4] * 0.25f + 1.0f);
    l_ = imin(imax(l_, 0), 256); t_ = imin(imax(t_, 0), 256);
    r_ = imin(imax(r_, 0), 256); b_ = imin(imax(b_, 0), 256);
    const float ch = (float)(b_ - t_);
    const float cw = (float)(r_ - l_);
    const bool transpose = ch > 1.5f * cw;
    const int chi = imax(b_ - t_, 1);
    const int cwi = imax(r_ - l_, 1);
    const float vscale = ((r_ > l_) && (b_ > t_)) ? 1.f : 0.f;

    {
        const int pos_l  = tid >> 2;
        const int corner = tid & 3;
        const int pos = q0 * 64 + pos_l;
        const int i = pos >> 5, j = pos & 31;
        const float fi = (float)i + 0.5f, fj = (float)j + 0.5f;
        float V = transpose ? (fj * ch * (1.f / 32.f) - 0.5f)
                            : (fi * ch * (1.f / 8.f)  - 0.5f);
        float U = transpose ? (fi * cw * (1.f / 8.f)  - 0.5f)
                            : (fj * cw * (1.f / 32.f) - 0.5f);
        V = fmaxf(V, 0.f); U = fmaxf(U, 0.f);
        float vf = floorf(V), uf = floorf(U);
        int y0 = imin((int)vf, chi - 1); int y1 = imin(y0 + 1, chi - 1);
        int x0 = imin((int)uf, cwi - 1); int x1 = imin(x0 + 1, cwi - 1);
        float wy = V - vf, wx = U - uf;
        int ay = imin(imax(t_ + ((corner & 2) ? y1 : y0), 0), 255);
        int ax = imin(imax(l_ + ((corner & 1) ? x1 : x0), 0), 255);
        float wgt = ((corner & 2) ? wy : (1.f - wy)) * ((corner & 1) ? wx : (1.f - wx));
        wts[pos_l][corner]  = wgt * masks[(size_t)roi * 65536 + ay * 256 + ax] * vscale;
        offs[pos_l][corner] = (ay * 256 + ax) * 32;   // u64 units per pixel row
    }
    __syncthreads();

    const int cq = tid & 31;              // channel quad: ch = 4*cq..4*cq+3
    const int pq = tid >> 5;              // 0..7
    const unsigned long long* fb = feat_u64 + (size_t)bi * (65536ull * 32ull) + cq;
    float* op = out + (size_t)roi * 32768 + (size_t)cq * 4 * 256 + q0 * 64;

#pragma unroll 2
    for (int po = 0; po < 8; ++po) {
        const int pos_l = po * 8 + pq;
        float a0 = 0.f, a1 = 0.f, a2 = 0.f, a3 = 0.f;
#pragma unroll
        for (int k = 0; k < 4; ++k) {
            unsigned long long u = fb[offs[pos_l][k]];
            float w = wts[pos_l][k];
            a0 += w * __uint_as_float((unsigned)(u)       << 16);
            a1 += w * __uint_as_float((unsigned)(u >> 16) << 16);
            a2 += w * __uint_as_float((unsigned)(u >> 32) << 16);
            a3 += w * __uint_as_float((unsigned)(u >> 48) << 16);
        }
        op[pos_l]       = a0;
        op[pos_l + 256] = a1;
        op[pos_l + 512] = a2;
        op[pos_l + 768] = a3;
    }
}

// ---------------------------------------------------------------------------
extern "C" void kernel_launch(void* const* d_in, const int* in_sizes, int n_in,
                              void* d_out, int out_size, void* d_ws, size_t ws_size,
                              hipStream_t stream) {
    const float* feats    = (const float*)d_in[0];
    const float* rois     = (const float*)d_in[1];
    const float* masks    = (const float*)d_in[2];
    const float* conv_w   = (const float*)d_in[3];
    const float* conv_b   = (const float*)d_in[4];
    const float* bn_gamma = (const float*)d_in[5];
    const float* bn_beta  = (const float*)d_in[6];
    const float* bn_mean  = (const float*)d_in[7];
    const float* bn_var   = (const float*)d_in[8];
    float* out = (float*)d_out;

    // ws layout: [wprep 576KB][zguard 64B][... to 1MB][feat_cl 64MB][fb16 4x32MB]
    unsigned short* wprep   = (unsigned short*)d_ws;
    unsigned short* zguard  = (unsigned short*)((char*)d_ws + 0x90000);
    unsigned short* feat_cl = (unsigned short*)((char*)d_ws + (1ull << 20));
    unsigned short* fb16    = (unsigned short*)((char*)d_ws + (1ull << 20) + (64ull << 20));

    const size_t need_merged = (1ull << 20) + (64ull << 20) + (128ull << 20);

    hipLaunchKernelGGL(wprep_kernel, dim3(1152), dim3(256), 0, stream,
                       conv_w, wprep, zguard);

    if (ws_size >= need_merged) {
        // merged path: one prep over all 4 images, one conv over all 4 images
        hipLaunchKernelGGL(prep_kernel, dim3(2048), dim3(256), 0, stream,
                           feats, fb16);
        hipLaunchKernelGGL(conv_bn_relu_kernel, dim3(2048), dim3(256), 0, stream,
                           fb16, conv_b, bn_gamma, bn_beta, bn_mean, bn_var,
                           wprep, zguard, feat_cl);
    } else {
        // fallback: per-batch loop reusing one fb16 image buffer (b folds to 0)
        for (int b = 0; b < 4; ++b) {
            hipLaunchKernelGGL(prep_kernel, dim3(512), dim3(256), 0, stream,
                               feats + (size_t)b * FEAT_IMG, fb16);
            hipLaunchKernelGGL(conv_bn_relu_kernel, dim3(512), dim3(256), 0, stream,
                               fb16, conv_b, bn_gamma, bn_beta, bn_mean, bn_var,
                               wprep, zguard, feat_cl + (size_t)b * FCL_IMG);
        }
    }

    hipLaunchKernelGGL(roi_gather_kernel, dim3(512), dim3(256), 0, stream,
                       rois, masks, (const unsigned long long*)feat_cl, out);
}

// Round 6
// 539.250 us; speedup vs baseline: 1.7725x; 1.1534x over previous
//
#include <hip/hip_runtime.h>

typedef __attribute__((ext_vector_type(8))) short short8;    // 8 bf16 = 4 VGPRs
typedef __attribute__((ext_vector_type(4))) float float4v;   // MFMA acc

static __device__ __forceinline__ unsigned short f2bf(float x) {
    unsigned u = __float_as_uint(x);
    return (unsigned short)((u + 0x7fffu + ((u >> 16) & 1u)) >> 16);  // RNE
}
static __device__ __forceinline__ int imin(int a, int b) { return a < b ? a : b; }
static __device__ __forceinline__ int imax(int a, int b) { return a > b ? a : b; }

// async global->LDS, 16B per lane; LDS side is wave-base + lane*16 (contiguous)
static __device__ __forceinline__ void gload_lds16(const void* g, void* l) {
    __builtin_amdgcn_global_load_lds(
        (const __attribute__((address_space(1))) void*)g,
        (__attribute__((address_space(3))) void*)l, 16, 0, 0);
}

// per-image strides (in elements)
#define FB16_IMG 16777216ull   // 8 chunks * 256h * 256w * 32cin shorts (32 MiB)
#define FCL_IMG   8388608ull   // 256h * 256w * 128cout shorts (16 MiB)
#define FEAT_IMG 16777216ull   // 256cin * 256h * 256w floats (64 MiB)
#define CHUNK_STRIDE 2097152   // shorts per chunk (65536 * 32)

// ---------------------------------------------------------------------------
// Kernel 0: repack conv weights fp32 -> bf16, [cin_chunk8][tap9][cout128][cin32]
//           + zero the 64B OOB guard block.  (unchanged, known-good)
// ---------------------------------------------------------------------------
__global__ void wprep_kernel(const float* __restrict__ conv_w,
                             unsigned short* __restrict__ wprep,
                             unsigned short* __restrict__ zguard) {
    if (blockIdx.x == 0 && threadIdx.x < 32) zguard[threadIdx.x] = 0;
    int e = blockIdx.x * 256 + threadIdx.x;           // 294912 total
    if (e >= 294912) return;
    int ci = e & 31;
    int t2 = e >> 5;
    int co = t2 & 127;
    int t3 = t2 >> 7;        // chunk*9 + tap
    int tap = t3 % 9;
    int chunk = t3 / 9;
    int cin = chunk * 32 + ci;
    int ty = tap / 3, tx = tap - ty * 3;
    wprep[e] = f2bf(conv_w[((co * 256 + cin) * 3 + ty) * 3 + tx]);
}

// ---------------------------------------------------------------------------
// Kernel 1: input repack fp32 NCHW -> bf16 [b][chunk8][h][w][cin32].
// ROUND-1 EXACT version (reverted): thread = one pixel, 32 scalar plane
// reads (256B/wave-instruction, coalesced), 4x16B CONSECUTIVE stores per
// thread (64B/thread, lines fully covered -> no write amplification).
// The round-3 "vectorized" variant caused 2.5x WRITE amplification
// (16B stores at 256B lane-stride -> partial-line evictions): 200us vs ~50us.
// ---------------------------------------------------------------------------
__global__ __launch_bounds__(256) void prep_kernel(const float* __restrict__ feats,
                                                   unsigned short* __restrict__ fb16) {
    const int bx = blockIdx.x;
    const int b  = bx >> 11;              // image (2048 blocks per image)
    const int r  = bx & 2047;             // chunk(8) x h(256)
    const int chunk = r >> 8;
    const int h = r & 255;
    const int w = threadIdx.x;
    const float* src = feats + (size_t)b * FEAT_IMG
                     + ((size_t)(chunk * 32) * 256 + h) * 256 + w;
    union { unsigned short u16[32]; short8 v8[4]; } p;
#pragma unroll
    for (int ci = 0; ci < 32; ++ci)
        p.u16[ci] = f2bf(src[(size_t)ci * 65536]);
    unsigned short* dst = fb16 + (size_t)b * FB16_IMG
                        + ((size_t)(chunk * 256 + h) * 256 + w) * 32;
#pragma unroll
    for (int k = 0; k < 4; ++k)
        *(short8*)(dst + k * 8) = p.v8[k];
}

// ---------------------------------------------------------------------------
// Kernel 2: conv3x3 + bias + BN + ReLU, implicit GEMM.  (round-5, known-good:
// ~65us, weight fragments hoisted per chunk + dy-reuse tap loop.)
// ---------------------------------------------------------------------------
__global__ __launch_bounds__(256, 2) void conv_bn_relu_kernel(
    const unsigned short* __restrict__ fb16_all,  // [b][chunk][h][w][cin32]
    const float* __restrict__ conv_b,
    const float* __restrict__ bn_gamma,
    const float* __restrict__ bn_beta,
    const float* __restrict__ bn_mean,
    const float* __restrict__ bn_var,
    const unsigned short* __restrict__ wprep,
    const unsigned short* __restrict__ zguard,
    unsigned short* __restrict__ feat_cl_all) {   // [b][h][w][128]

    __shared__ __align__(16) unsigned short in_lds[6 * 34 * 32];  // 13056 B
    __shared__ float aL[128], bL[128];

    const int tid = threadIdx.x;
    const int b   = blockIdx.x >> 9;       // image (512 blocks per image)
    const int rem = blockIdx.x & 511;      // ht(64) x wt(8)
    const int h0  = (rem >> 3) * 4;
    const int w0  = (rem & 7) * 32;

    const unsigned short* fb16 = fb16_all + (size_t)b * FB16_IMG;
    unsigned short* feat_cl_b  = feat_cl_all + (size_t)b * FCL_IMG;

    if (tid < 128) {
        float s = bn_gamma[tid] * rsqrtf(bn_var[tid] + 1e-5f);
        aL[tid] = s;
        bL[tid] = (conv_b[tid] - bn_mean[tid]) * s + bn_beta[tid];
    }

    const int wave = tid >> 6;
    const int lane = tid & 63;
    const int q    = lane >> 4;
    const int l15  = lane & 15;

    // ---- staging descriptors (round-1 exact): 816 units, wave*204 ---------
    // unit u: row=u/136, col=(u%136)>>2, part=(u%136)&3
    int  off_s[4];          // element offset into fb16 chunk slice (shorts)
    int  lds_s[4];          // LDS short offset (= u*8, lane-contiguous)
    bool oob_s[4];
#pragma unroll
    for (int i = 0; i < 4; ++i) {
        int u = wave * 204 + i * 64 + lane;   // i==3: only lane<12 used
        int row = u / 136;
        int r2  = u - row * 136;
        int col = r2 >> 2;
        int part = r2 & 3;
        int gh = h0 - 1 + row;
        int gw = w0 - 1 + col;
        oob_s[i] = ((unsigned)gh > 255u) || ((unsigned)gw > 255u);
        off_s[i] = (gh * 256 + gw) * 32 + part * 8;
        lds_s[i] = u * 8;
    }

    float4v acc[2][8];
#pragma unroll
    for (int a = 0; a < 2; ++a)
#pragma unroll
        for (int p = 0; p < 8; ++p)
            acc[a][p] = (float4v){0.f, 0.f, 0.f, 0.f};

    for (int c = 0; c < 8; ++c) {
        const unsigned short* fb = fb16 + (size_t)c * CHUNK_STRIDE;
        // ---- issue staging DMAs ----
#pragma unroll
        for (int i = 0; i < 3; ++i) {
            const unsigned short* gp = oob_s[i] ? zguard : (fb + off_s[i]);
            gload_lds16(gp, &in_lds[lds_s[i]]);
        }
        if (lane < 12) {
            const unsigned short* gp = oob_s[3] ? zguard : (fb + off_s[3]);
            gload_lds16(gp, &in_lds[lds_s[3]]);
        }

        // ---- hoist all 18 weight fragments for this chunk (independent
        //      L2 loads; overlap the staging drain below) ----
        const short8* wc = (const short8*)wprep + (size_t)c * 9 * 512;
        short8 w0f[9], w1f[9];
#pragma unroll
        for (int tap = 0; tap < 9; ++tap) {
            w0f[tap] = wc[tap * 512 + (wave * 32 + l15) * 4 + q];
            w1f[tap] = wc[tap * 512 + (wave * 32 + 16 + l15) * 4 + q];
        }

        __syncthreads();   // drains DMAs (and the weight burst)

        // ---- dy-reuse tap loop: 36 LDS reads, 144 MFMAs per wave ----
#pragma unroll
        for (int dx = 0; dx < 3; ++dx) {
#pragma unroll
            for (int rho = 0; rho < 6; ++rho) {
#pragma unroll
                for (int half = 0; half < 2; ++half) {
                    short8 bf = *(const short8*)
                        &in_lds[(rho * 34 + (half * 16 + l15 + dx)) * 32 + q * 8];
#pragma unroll
                    for (int dy = 0; dy < 3; ++dy) {
                        const int r = rho - dy;
                        if (r >= 0 && r <= 3) {
                            const int tap = dy * 3 + dx;
                            const int pt  = r * 2 + half;
                            acc[0][pt] = __builtin_amdgcn_mfma_f32_16x16x32_bf16(
                                w0f[tap], bf, acc[0][pt], 0, 0, 0);
                            acc[1][pt] = __builtin_amdgcn_mfma_f32_16x16x32_bf16(
                                w1f[tap], bf, acc[1][pt], 0, 0, 0);
                        }
                    }
                }
            }
        }
        __syncthreads();
    }

    // ---- epilogue: bias+BN+ReLU, channels-last bf16 store (round-1 exact) --
#pragma unroll
    for (int ct = 0; ct < 2; ++ct) {
        const int coutb = wave * 32 + ct * 16 + q * 4;
        const float s0 = aL[coutb + 0], s1 = aL[coutb + 1];
        const float s2 = aL[coutb + 2], s3 = aL[coutb + 3];
        const float o0 = bL[coutb + 0], o1 = bL[coutb + 1];
        const float o2 = bL[coutb + 2], o3 = bL[coutb + 3];
#pragma unroll
        for (int pt = 0; pt < 8; ++pt) {
            const int r  = pt >> 1;
            const int cl = (pt & 1) * 16 + l15;
            float4v v = acc[ct][pt];
            unsigned short p0 = f2bf(fmaxf(v[0] * s0 + o0, 0.f));
            unsigned short p1 = f2bf(fmaxf(v[1] * s1 + o1, 0.f));
            unsigned short p2 = f2bf(fmaxf(v[2] * s2 + o2, 0.f));
            unsigned short p3 = f2bf(fmaxf(v[3] * s3 + o3, 0.f));
            unsigned long long pk = (unsigned long long)p0
                                  | ((unsigned long long)p1 << 16)
                                  | ((unsigned long long)p2 << 32)
                                  | ((unsigned long long)p3 << 48);
            size_t off = ((size_t)((h0 + r) * 256 + (w0 + cl))) * 128 + coutb;
            *(unsigned long long*)(feat_cl_b + off) = pk;
        }
    }
}

// ---------------------------------------------------------------------------
// Kernel 3: masked bilinear RoI gather.  (unchanged)
// ---------------------------------------------------------------------------
__global__ __launch_bounds__(256) void roi_gather_kernel(
    const float* __restrict__ rois,
    const float* __restrict__ masks,
    const unsigned long long* __restrict__ feat_u64,   // feat_cl as 4ch/8B
    float* __restrict__ out) {

    __shared__ int   offs[64][4];
    __shared__ float wts[64][4];

    const int blk = blockIdx.x;            // 512: roi(128) x q0(4)
    const int roi = blk >> 2;
    const int q0  = blk & 3;
    const int tid = threadIdx.x;

    const float* rp = rois + roi * 5;
    const int bi = (int)rp[0];
    int l_ = (int)(rp[1] * 0.25f - 1.0f);
    int t_ = (int)(rp[2] * 0.25f - 1.0f);
    int r_ = (int)(rp[3] * 0.25f + 1.0f);
    int b_ = (int)(rp[4] * 0.25f + 1.0f);
    l_ = imin(imax(l_, 0), 256); t_ = imin(imax(t_, 0), 256);
    r_ = imin(imax(r_, 0), 256); b_ = imin(imax(b_, 0), 256);
    const float ch = (float)(b_ - t_);
    const float cw = (float)(r_ - l_);
    const bool transpose = ch > 1.5f * cw;
    const int chi = imax(b_ - t_, 1);
    const int cwi = imax(r_ - l_, 1);
    const float vscale = ((r_ > l_) && (b_ > t_)) ? 1.f : 0.f;

    {
        const int pos_l  = tid >> 2;
        const int corner = tid & 3;
        const int pos = q0 * 64 + pos_l;
        const int i = pos >> 5, j = pos & 31;
        const float fi = (float)i + 0.5f, fj = (float)j + 0.5f;
        float V = transpose ? (fj * ch * (1.f / 32.f) - 0.5f)
                            : (fi * ch * (1.f / 8.f)  - 0.5f);
        float U = transpose ? (fi * cw * (1.f / 8.f)  - 0.5f)
                            : (fj * cw * (1.f / 32.f) - 0.5f);
        V = fmaxf(V, 0.f); U = fmaxf(U, 0.f);
        float vf = floorf(V), uf = floorf(U);
        int y0 = imin((int)vf, chi - 1); int y1 = imin(y0 + 1, chi - 1);
        int x0 = imin((int)uf, cwi - 1); int x1 = imin(x0 + 1, cwi - 1);
        float wy = V - vf, wx = U - uf;
        int ay = imin(imax(t_ + ((corner & 2) ? y1 : y0), 0), 255);
        int ax = imin(imax(l_ + ((corner & 1) ? x1 : x0), 0), 255);
        float wgt = ((corner & 2) ? wy : (1.f - wy)) * ((corner & 1) ? wx : (1.f - wx));
        wts[pos_l][corner]  = wgt * masks[(size_t)roi * 65536 + ay * 256 + ax] * vscale;
        offs[pos_l][corner] = (ay * 256 + ax) * 32;   // u64 units per pixel row
    }
    __syncthreads();

    const int cq = tid & 31;              // channel quad: ch = 4*cq..4*cq+3
    const int pq = tid >> 5;              // 0..7
    const unsigned long long* fb = feat_u64 + (size_t)bi * (65536ull * 32ull) + cq;
    float* op = out + (size_t)roi * 32768 + (size_t)cq * 4 * 256 + q0 * 64;

#pragma unroll 2
    for (int po = 0; po < 8; ++po) {
        const int pos_l = po * 8 + pq;
        float a0 = 0.f, a1 = 0.f, a2 = 0.f, a3 = 0.f;
#pragma unroll
        for (int k = 0; k < 4; ++k) {
            unsigned long long u = fb[offs[pos_l][k]];
            float w = wts[pos_l][k];
            a0 += w * __uint_as_float((unsigned)(u)       << 16);
            a1 += w * __uint_as_float((unsigned)(u >> 16) << 16);
            a2 += w * __uint_as_float((unsigned)(u >> 32) << 16);
            a3 += w * __uint_as_float((unsigned)(u >> 48) << 16);
        }
        op[pos_l]       = a0;
        op[pos_l + 256] = a1;
        op[pos_l + 512] = a2;
        op[pos_l + 768] = a3;
    }
}

// ---------------------------------------------------------------------------
extern "C" void kernel_launch(void* const* d_in, const int* in_sizes, int n_in,
                              void* d_out, int out_size, void* d_ws, size_t ws_size,
                              hipStream_t stream) {
    const float* feats    = (const float*)d_in[0];
    const float* rois     = (const float*)d_in[1];
    const float* masks    = (const float*)d_in[2];
    const float* conv_w   = (const float*)d_in[3];
    const float* conv_b   = (const float*)d_in[4];
    const float* bn_gamma = (const float*)d_in[5];
    const float* bn_beta  = (const float*)d_in[6];
    const float* bn_mean  = (const float*)d_in[7];
    const float* bn_var   = (const float*)d_in[8];
    float* out = (float*)d_out;

    // ws layout: [wprep 576KB][zguard 64B][... to 1MB][feat_cl 64MB][fb16 4x32MB]
    unsigned short* wprep   = (unsigned short*)d_ws;
    unsigned short* zguard  = (unsigned short*)((char*)d_ws + 0x90000);
    unsigned short* feat_cl = (unsigned short*)((char*)d_ws + (1ull << 20));
    unsigned short* fb16    = (unsigned short*)((char*)d_ws + (1ull << 20) + (64ull << 20));

    const size_t need_merged = (1ull << 20) + (64ull << 20) + (128ull << 20);

    hipLaunchKernelGGL(wprep_kernel, dim3(1152), dim3(256), 0, stream,
                       conv_w, wprep, zguard);

    if (ws_size >= need_merged) {
        // merged path: one prep over all 4 images, one conv over all 4 images
        hipLaunchKernelGGL(prep_kernel, dim3(8192), dim3(256), 0, stream,
                           feats, fb16);
        hipLaunchKernelGGL(conv_bn_relu_kernel, dim3(2048), dim3(256), 0, stream,
                           fb16, conv_b, bn_gamma, bn_beta, bn_mean, bn_var,
                           wprep, zguard, feat_cl);
    } else {
        // fallback: per-batch loop reusing one fb16 image buffer (b folds to 0)
        for (int b = 0; b < 4; ++b) {
            hipLaunchKernelGGL(prep_kernel, dim3(2048), dim3(256), 0, stream,
                               feats + (size_t)b * FEAT_IMG, fb16);
            hipLaunchKernelGGL(conv_bn_relu_kernel, dim3(512), dim3(256), 0, stream,
                               fb16, conv_b, bn_gamma, bn_beta, bn_mean, bn_var,
                               wprep, zguard, feat_cl + (size_t)b * FCL_IMG);
        }
    }

    hipLaunchKernelGGL(roi_gather_kernel, dim3(512), dim3(256), 0, stream,
                       rois, masks, (const unsigned long long*)feat_cl, out);
}